// Round 22
// baseline (266.748 us; speedup 1.0000x reference)
//
#include <hip/hip_runtime.h>
#include <hip/hip_bf16.h>

#define D_MODEL 1024
#define D_FF    4096
#define SEQ_LEN 2048
#define NBATCH  4
#define NROWS   (NBATCH*SEQ_LEN)   // 8192
#define NCHUNK  32
#define CHUNK_L (SEQ_LEN/NCHUNK)   // 64
#define LN_EPS  1e-5f

typedef __hip_bfloat16 bf16;
typedef __attribute__((ext_vector_type(8))) short bf16x8;
typedef __attribute__((ext_vector_type(4))) float f32x4;

// async global->LDS, 16B per lane; LDS dest is wave-uniform base + lane*16
__device__ __forceinline__ void gload16(const bf16* g, bf16* l) {
    __builtin_amdgcn_global_load_lds(
        (const __attribute__((address_space(1))) void*)g,
        (__attribute__((address_space(3))) void*)l, 16, 0, 0);
}

// ---------------- cast f32 -> bf16, vectorized ----------------
__global__ void cast4(const float4* __restrict__ in, ushort4* __restrict__ out, int n4) {
    int i = blockIdx.x * blockDim.x + threadIdx.x;
    if (i < n4) {
        float4 v = in[i];
        union { ushort4 u; bf16 b[4]; } cv;
        cv.b[0] = __float2bfloat16(v.x); cv.b[1] = __float2bfloat16(v.y);
        cv.b[2] = __float2bfloat16(v.z); cv.b[3] = __float2bfloat16(v.w);
        out[i] = cv.u;
    }
}

// ---------------- p, p^64 from phazor ----------------
__global__ void compute_pvec(const float* __restrict__ phz, float* __restrict__ pv) {
    int d = blockIdx.x * blockDim.x + threadIdx.x;
    if (d >= D_MODEL) return;
    float re = phz[2*d], im = phz[2*d+1];
    float r2 = re*re + im*im;
    float mag = expf(-r2);
    float pr, pim;
    if (r2 > 0.f) { float inv = mag / sqrtf(r2); pr = re*inv; pim = im*inv; }
    else          { pr = mag; pim = 0.f; }
    float ar = pr, ai = pim;
    #pragma unroll
    for (int i = 0; i < 6; i++) { float nr = ar*ar - ai*ai; float ni = 2.f*ar*ai; ar = nr; ai = ni; }
    pv[d]            = pr;
    pv[D_MODEL+d]    = pim;
    pv[2*D_MODEL+d]  = ar;
    pv[3*D_MODEL+d]  = ai;
}

// ---------------- LayerNorm: writes xn (bf16) + raw-x cast (bf16) ----------------
__global__ __launch_bounds__(256) void ln_fused(const float* __restrict__ x,
                                                const float* __restrict__ g,
                                                const float* __restrict__ bta,
                                                bf16*  __restrict__ outb,
                                                bf16*  __restrict__ rawb)
{
    int row = blockIdx.x;
    int tid = threadIdx.x;
    const float4* xr = (const float4*)(x + (size_t)row * D_MODEL);
    float4 v = xr[tid];
    if (rawb) {
        union { ushort4 u; bf16 b[4]; } cv;
        cv.b[0]=__float2bfloat16(v.x); cv.b[1]=__float2bfloat16(v.y);
        cv.b[2]=__float2bfloat16(v.z); cv.b[3]=__float2bfloat16(v.w);
        ((ushort4*)(rawb + (size_t)row * D_MODEL))[tid] = cv.u;
    }
    float s  = v.x + v.y + v.z + v.w;
    float s2 = v.x*v.x + v.y*v.y + v.z*v.z + v.w*v.w;
    for (int off = 32; off; off >>= 1) { s += __shfl_down(s, off); s2 += __shfl_down(s2, off); }
    __shared__ float red[8];
    int wid = tid >> 6, lane = tid & 63;
    if (lane == 0) { red[wid] = s; red[4+wid] = s2; }
    __syncthreads();
    if (tid == 0) {
        red[0] = red[0]+red[1]+red[2]+red[3];
        red[4] = red[4]+red[5]+red[6]+red[7];
    }
    __syncthreads();
    float mu  = red[0] * (1.f/D_MODEL);
    float var = red[4] * (1.f/D_MODEL) - mu*mu;
    float rstd = rsqrtf(var + LN_EPS);
    float4 gv = ((const float4*)g)[tid];
    float4 bv = ((const float4*)bta)[tid];
    union { ushort4 u; bf16 b[4]; } cv;
    cv.b[0] = __float2bfloat16((v.x-mu)*rstd*gv.x + bv.x);
    cv.b[1] = __float2bfloat16((v.y-mu)*rstd*gv.y + bv.y);
    cv.b[2] = __float2bfloat16((v.z-mu)*rstd*gv.z + bv.z);
    cv.b[3] = __float2bfloat16((v.w-mu)*rstd*gv.w + bv.w);
    ((ushort4*)(outb + (size_t)row * D_MODEL))[tid] = cv.u;
}

// ---------------- LN (bf16 in -> bf16 out): x3 = LN(x2b) ----------------
__global__ __launch_bounds__(256) void ln_b(const bf16* __restrict__ xin,
                                            const float* __restrict__ g,
                                            const float* __restrict__ bta,
                                            bf16*  __restrict__ outb)
{
    int row = blockIdx.x;
    int tid = threadIdx.x;
    size_t base = (size_t)row * D_MODEL + tid*4;
    union { ushort4 u; bf16 b[4]; } iv;
    iv.u = *(const ushort4*)(xin + base);
    float4 v;
    v.x = __bfloat162float(iv.b[0]); v.y = __bfloat162float(iv.b[1]);
    v.z = __bfloat162float(iv.b[2]); v.w = __bfloat162float(iv.b[3]);
    float s  = v.x + v.y + v.z + v.w;
    float s2 = v.x*v.x + v.y*v.y + v.z*v.z + v.w*v.w;
    for (int off = 32; off; off >>= 1) { s += __shfl_down(s, off); s2 += __shfl_down(s2, off); }
    __shared__ float red[8];
    int wid = tid >> 6, lane = tid & 63;
    if (lane == 0) { red[wid] = s; red[4+wid] = s2; }
    __syncthreads();
    if (tid == 0) {
        red[0] = red[0]+red[1]+red[2]+red[3];
        red[4] = red[4]+red[5]+red[6]+red[7];
    }
    __syncthreads();
    float mu  = red[0] * (1.f/D_MODEL);
    float var = red[4] * (1.f/D_MODEL) - mu*mu;
    float rstd = rsqrtf(var + LN_EPS);
    float4 gv = ((const float4*)g)[tid];
    float4 bv = ((const float4*)bta)[tid];
    union { ushort4 u; bf16 b[4]; } cv;
    cv.b[0] = __float2bfloat16((v.x-mu)*rstd*gv.x + bv.x);
    cv.b[1] = __float2bfloat16((v.y-mu)*rstd*gv.y + bv.y);
    cv.b[2] = __float2bfloat16((v.z-mu)*rstd*gv.z + bv.z);
    cv.b[3] = __float2bfloat16((v.w-mu)*rstd*gv.w + bv.w);
    *(ushort4*)(outb + base) = cv.u;
}

// ---------------- scan pass 1: per-chunk local state (zero init), bf16 input ----------------
__global__ __launch_bounds__(256) void scan_pass1(const bf16* __restrict__ xn,
                                                  const float* __restrict__ pv,
                                                  const float* __restrict__ pini,
                                                  float* __restrict__ Sc)
{
    int d = blockIdx.x * 256 + threadIdx.x;
    int c = blockIdx.y, b = blockIdx.z;
    float pr = pv[d], pim = pv[D_MODEL+d];
    float icr = pini[2*d], ici = pini[2*d+1];
    float Sr = 0.f, Si = 0.f;
    const bf16* xp = xn + ((size_t)b*SEQ_LEN + c*CHUNK_L) * D_MODEL + d;
    #pragma unroll 8
    for (int i = 0; i < CHUNK_L; i++) {
        float xv = __bfloat162float(xp[(size_t)i * D_MODEL]);
        float nr = pr*Sr - pim*Si + icr*xv;
        float ni = pr*Si + pim*Sr + ici*xv;
        Sr = nr; Si = ni;
    }
    size_t o = ((size_t)b*NCHUNK + c) * D_MODEL + d;
    Sc[2*o] = Sr; Sc[2*o+1] = Si;
}

// ---------------- scan pass 2: exclusive prefix over chunks (init = hidden) ----------------
__global__ __launch_bounds__(256) void scan_prefix(const float* __restrict__ Sc,
                                                   const float* __restrict__ pv,
                                                   const float* __restrict__ hr,
                                                   const float* __restrict__ hi,
                                                   float* __restrict__ pref)
{
    int d = blockIdx.x * 256 + threadIdx.x;
    int b = blockIdx.y;
    float qr = pv[2*D_MODEL+d], qi = pv[3*D_MODEL+d];   // p^64
    float Ur = hr[b*D_MODEL+d], Ui = hi[b*D_MODEL+d];
    for (int c = 0; c < NCHUNK; c++) {
        size_t o = ((size_t)b*NCHUNK + c) * D_MODEL + d;
        pref[2*o] = Ur; pref[2*o+1] = Ui;
        float sr = Sc[2*o], si = Sc[2*o+1];
        float nr = qr*Ur - qi*Ui + sr;
        float ni = qr*Ui + qi*Ur + si;
        Ur = nr; Ui = ni;
    }
}

// ---------------- scan pass 3 + gate fusion ----------------
// writes cwp = U (output 1) AND x2b = cwp_real * y + x (bf16), eliminating the
// separate gate_ln stream pass (r21: gate_ln read cwp+x+y = 112MB; this adds
// only y+xbf reads (32MB bf16) and the x2b write (16MB) to the scan pass).
__global__ __launch_bounds__(256) void scan_pass2g(const bf16* __restrict__ xn,
                                                   const float* __restrict__ pv,
                                                   const float* __restrict__ pini,
                                                   const float* __restrict__ pref,
                                                   const bf16* __restrict__ y,
                                                   const bf16* __restrict__ xb,
                                                   float* __restrict__ cwp,
                                                   bf16*  __restrict__ x2b,
                                                   int interleaved)
{
    int d = blockIdx.x * 256 + threadIdx.x;
    int c = blockIdx.y, b = blockIdx.z;
    float pr = pv[d], pim = pv[D_MODEL+d];
    float icr = pini[2*d], ici = pini[2*d+1];
    size_t po = ((size_t)b*NCHUNK + c) * D_MODEL + d;
    float Ur = pref[2*po], Ui = pref[2*po+1];
    size_t base = ((size_t)b*SEQ_LEN + c*CHUNK_L) * D_MODEL + d;
    const bf16* xp = xn + base;
    const bf16* yp = y  + base;
    const bf16* rp = xb + base;
    bf16* x2p = x2b + base;
    if (interleaved) {
        float2* cp = (float2*)cwp + base;
        #pragma unroll 8
        for (int i = 0; i < CHUNK_L; i++) {
            float xv = __bfloat162float(xp[(size_t)i * D_MODEL]);
            float nr = pr*Ur - pim*Ui + icr*xv;
            float ni = pr*Ui + pim*Ur + ici*xv;
            Ur = nr; Ui = ni;
            cp[(size_t)i * D_MODEL] = make_float2(Ur, Ui);
            float x2 = Ur * __bfloat162float(yp[(size_t)i * D_MODEL])
                     + __bfloat162float(rp[(size_t)i * D_MODEL]);
            x2p[(size_t)i * D_MODEL] = __float2bfloat16(x2);
        }
    } else {
        float* cp = cwp + base;
        #pragma unroll 8
        for (int i = 0; i < CHUNK_L; i++) {
            float xv = __bfloat162float(xp[(size_t)i * D_MODEL]);
            float nr = pr*Ur - pim*Ui + icr*xv;
            float ni = pr*Ui + pim*Ur + ici*xv;
            Ur = nr; Ui = ni;
            cp[(size_t)i * D_MODEL] = Ur;
            float x2 = Ur * __bfloat162float(yp[(size_t)i * D_MODEL])
                     + __bfloat162float(rp[(size_t)i * D_MODEL]);
            x2p[(size_t)i * D_MODEL] = __float2bfloat16(x2);
        }
    }
}

// ---------------- shared epilogue ----------------
// EPI 1: h = silu(acc+bias) -> bf16 ; EPI 2: out = acc + bias + x2b (bf16 residual) -> f32
template<int EPI>
__device__ __forceinline__ void epi_store(float v, size_t idx,
                                          const bf16* e0b, float* outf, bf16* outb)
{
    if (EPI == 1) {
        float yv = v / (1.f + __expf(-v));
        outb[idx] = __float2bfloat16(yv);
    } else {
        outf[idx] = v + __bfloat162float(e0b[idx]);
    }
}

// ---------------- bf16 MFMA GEMM 128x128: depth-3 LDS pipeline (r6/r8-proven) ----------------
#define BM 128
#define BN 128
#define BK 32

template<int EPI>
__global__ __launch_bounds__(256) void gemm_bt(const bf16* __restrict__ A,
                                               const bf16* __restrict__ Bt,
                                               const float* __restrict__ bias,
                                               const bf16* __restrict__ e0b,
                                               float* __restrict__ outf,
                                               bf16*  __restrict__ outb,
                                               int M, int N, int K)
{
    __shared__ __align__(16) bf16 As[3][BM*BK];
    __shared__ __align__(16) bf16 Bs[3][BM*BK];
    int tid = threadIdx.x;
    int m0 = blockIdx.x * BM;
    int n0 = blockIdx.y * BN;

    int wid = tid >> 6, lane = tid & 63;
    int wm = (wid >> 1) * 64, wn = (wid & 1) * 64;
    int lr = lane & 15;
    int lkc = lane >> 4;

    int rl = lane >> 2;
    int cS = (lane & 3) ^ ((rl >> 1) & 3);
    const bf16* gA0 = A  + (size_t)(m0 +      wid*16 + rl) * K + cS*8;
    const bf16* gA1 = A  + (size_t)(m0 + 64 + wid*16 + rl) * K + cS*8;
    const bf16* gB0 = Bt + (size_t)(n0 +      wid*16 + rl) * K + cS*8;
    const bf16* gB1 = Bt + (size_t)(n0 + 64 + wid*16 + rl) * K + cS*8;
    int lo0 = (     wid*16) * BK;
    int lo1 = (64 + wid*16) * BK;

    int keyr = (lr >> 1) & 3;
    int cR = (lkc ^ keyr) * 8;
    int offA[4], offB[4];
    #pragma unroll
    for (int i = 0; i < 4; i++) {
        offA[i] = (wm + i*16 + lr) * BK + cR;
        offB[i] = (wn + i*16 + lr) * BK + cR;
    }

    int nt = K / BK;
    auto stage = [&](int slot, int tile) {
        int k0 = tile * BK;
        gload16(gA0 + k0, &As[slot][lo0]);
        gload16(gA1 + k0, &As[slot][lo1]);
        gload16(gB0 + k0, &Bs[slot][lo0]);
        gload16(gB1 + k0, &Bs[slot][lo1]);
    };
    f32x4 acc[4][4] = {};
    auto compute = [&](int slot) {
        bf16x8 af[4], bfv[4];
        #pragma unroll
        for (int i = 0; i < 4; i++) {
            af[i]  = *(const bf16x8*)&As[slot][offA[i]];
            bfv[i] = *(const bf16x8*)&Bs[slot][offB[i]];
        }
        #pragma unroll
        for (int i = 0; i < 4; i++)
            #pragma unroll
            for (int j = 0; j < 4; j++)
                acc[i][j] = __builtin_amdgcn_mfma_f32_16x16x32_bf16(af[i], bfv[j], acc[i][j], 0, 0, 0);
    };

    stage(0, 0); stage(1, 1); stage(2, 2);

    int s = 0;
    for (int t = 0; t < nt - 3; ++t) {
        asm volatile("s_waitcnt vmcnt(8)" ::: "memory");
        __builtin_amdgcn_s_barrier();
        __builtin_amdgcn_sched_barrier(0);
        compute(s);
        asm volatile("" ::: "memory");
        __builtin_amdgcn_s_barrier();
        stage(s, t + 3);
        s = (s == 2) ? 0 : s + 1;
    }
    asm volatile("s_waitcnt vmcnt(8)" ::: "memory");
    __builtin_amdgcn_s_barrier();
    __builtin_amdgcn_sched_barrier(0);
    compute(s);
    s = (s == 2) ? 0 : s + 1;
    asm volatile("s_waitcnt vmcnt(4)" ::: "memory");
    __builtin_amdgcn_s_barrier();
    __builtin_amdgcn_sched_barrier(0);
    compute(s);
    s = (s == 2) ? 0 : s + 1;
    asm volatile("s_waitcnt vmcnt(0)" ::: "memory");
    __builtin_amdgcn_s_barrier();
    __builtin_amdgcn_sched_barrier(0);
    compute(s);

    int mrow = 4 * (lane >> 4);
    #pragma unroll
    for (int i = 0; i < 4; i++) {
        #pragma unroll
        for (int j = 0; j < 4; j++) {
            int nb = n0 + wn + j*16 + lr;
            float bb = bias[nb];
            #pragma unroll
            for (int r = 0; r < 4; r++) {
                int m = m0 + wm + i*16 + mrow + r;
                size_t idx = (size_t)m * N + nb;
                epi_store<EPI>(acc[i][j][r] + bb, idx, e0b, outf, outb);
            }
        }
    }
}

// ---------------- bf16 MFMA GEMM 256x256: 2-phase counted-vmcnt pipeline (r13-verified) ----------------
#define TM 256
#define TN 256

__global__ __launch_bounds__(512, 2) void gemm256p(const bf16* __restrict__ A,
                                                   const bf16* __restrict__ Bt,
                                                   const float* __restrict__ bias,
                                                   bf16* __restrict__ outb,
                                                   int M, int N, int K)
{
    __shared__ __align__(16) bf16 As[3][TM*BK];
    __shared__ __align__(16) bf16 Bs[3][TN*BK];
    int tid = threadIdx.x;
    int m0 = blockIdx.x * TM;
    int n0 = blockIdx.y * TN;

    int wid = tid >> 6, lane = tid & 63;
    int wr = wid >> 2, wc = wid & 3;       // 2 x 4 wave grid
    int wm = wr * 128, wn = wc * 64;
    int lr = lane & 15;
    int lkc = lane >> 4;

    int rs = tid >> 2;                     // 0..127
    int cS = (tid & 3) ^ ((rs >> 1) & 3);
    const bf16* gA = A  + (size_t)m0 * K + cS*8;
    const bf16* gB = Bt + (size_t)n0 * K + cS*8;
    int ldst = tid * 8;

    int keyr = (lr >> 1) & 3;
    int cR = (lkc ^ keyr) * 8;
    int offA[8], offB[4];
    #pragma unroll
    for (int i = 0; i < 8; i++) offA[i] = (wm + i*16 + lr) * BK + cR;
    #pragma unroll
    for (int j = 0; j < 4; j++) offB[j] = (wn + j*16 + lr) * BK + cR;

    int nt = K / BK;                       // 32 for K=1024
    auto stA = [&](int slot, int tile) {
        int k0 = tile * BK;
        gload16(gA + (size_t)rs * K + k0,         &As[slot][ldst]);
        gload16(gA + (size_t)(128 + rs) * K + k0, &As[slot][4096 + ldst]);
    };
    auto stB = [&](int slot, int tile) {
        int k0 = tile * BK;
        gload16(gB + (size_t)rs * K + k0,         &Bs[slot][ldst]);
        gload16(gB + (size_t)(128 + rs) * K + k0, &Bs[slot][4096 + ldst]);
    };

    f32x4 acc[8][4] = {};
    stA(0, 0); stB(0, 0); stA(1, 1); stB(1, 1); stB(2, 2);

    int s = 0;
    for (int t = 0; t < nt; ++t) {
        int sA = (s >= 1) ? s - 1 : 2;     // (s+2)%3
        if (t < nt - 2)       { asm volatile("s_waitcnt vmcnt(6)" ::: "memory"); }
        else if (t == nt - 2) { asm volatile("s_waitcnt vmcnt(4)" ::: "memory"); }
        else                  { asm volatile("s_waitcnt vmcnt(0)" ::: "memory"); }
        __builtin_amdgcn_s_barrier();
        asm volatile("" ::: "memory");
        bf16x8 af0[4], bfv[4];
        #pragma unroll
        for (int i = 0; i < 4; i++) af0[i] = *(const bf16x8*)&As[s][offA[i]];
        #pragma unroll
        for (int j = 0; j < 4; j++) bfv[j] = *(const bf16x8*)&Bs[s][offB[j]];
        if (t + 2 < nt) stA(sA, t + 2);
        asm volatile("s_waitcnt lgkmcnt(0)" ::: "memory");
        __builtin_amdgcn_sched_barrier(0);
        __builtin_amdgcn_s_setprio(1);
        #pragma unroll
        for (int i = 0; i < 4; i++)
            #pragma unroll
            for (int j = 0; j < 4; j++)
                acc[i][j] = __builtin_amdgcn_mfma_f32_16x16x32_bf16(af0[i], bfv[j], acc[i][j], 0, 0, 0);
        __builtin_amdgcn_s_setprio(0);
        __builtin_amdgcn_s_barrier();
        asm volatile("" ::: "memory");
        bf16x8 af1[4];
        #pragma unroll
        for (int i = 0; i < 4; i++) af1[i] = *(const bf16x8*)&As[s][offA[4+i]];
        if (t + 3 < nt) stB(s, t + 3);
        asm volatile("s_waitcnt lgkmcnt(0)" ::: "memory");
        __builtin_amdgcn_sched_barrier(0);
        __builtin_amdgcn_s_setprio(1);
        #pragma unroll
        for (int i = 0; i < 4; i++)
            #pragma unroll
            for (int j = 0; j < 4; j++)
                acc[4+i][j] = __builtin_amdgcn_mfma_f32_16x16x32_bf16(af1[i], bfv[j], acc[4+i][j], 0, 0, 0);
        __builtin_amdgcn_s_setprio(0);
        s = (s == 2) ? 0 : s + 1;
    }
    asm volatile("s_waitcnt vmcnt(0)" ::: "memory");

    int mrow = 4 * (lane >> 4);
    #pragma unroll
    for (int i = 0; i < 8; i++) {
        #pragma unroll
        for (int j = 0; j < 4; j++) {
            int nb = n0 + wn + j*16 + lr;
            float bb = bias[nb];
            #pragma unroll
            for (int r = 0; r < 4; r++) {
                int m = m0 + wm + i*16 + mrow + r;
                size_t idx = (size_t)m * N + nb;
                float v = acc[i][j][r] + bb;
                float yv = v / (1.f + __expf(-v));
                outb[idx] = __float2bfloat16(yv);
            }
        }
    }
}

extern "C" void kernel_launch(void* const* d_in, const int* in_sizes, int n_in,
                              void* d_out, int out_size, void* d_ws, size_t ws_size,
                              hipStream_t stream)
{
    const float* x    = (const float*)d_in[0];
    const float* hr   = (const float*)d_in[1];
    const float* hi   = (const float*)d_in[2];
    const float* pini = (const float*)d_in[3];
    const float* phz  = (const float*)d_in[4];
    const float* fcw  = (const float*)d_in[5];
    const float* fcb  = (const float*)d_in[6];
    const float* w1   = (const float*)d_in[7];
    const float* b1   = (const float*)d_in[8];
    const float* w2   = (const float*)d_in[9];
    const float* b2   = (const float*)d_in[10];
    const float* lng  = (const float*)d_in[11];
    const float* lnb  = (const float*)d_in[12];

    float* out = (float*)d_out;
    float* cwp = out + (size_t)NROWS * D_MODEL;
    int interleaved = (out_size >= NROWS * D_MODEL * 3) ? 1 : 0;

    char* ws = (char*)d_ws;
    size_t off = 0;
    bf16*  wfcb = (bf16*)(ws + off);  off += (size_t)D_MODEL*D_MODEL*2;
    bf16*  w1b  = (bf16*)(ws + off);  off += (size_t)D_FF*D_MODEL*2;
    bf16*  w2b  = (bf16*)(ws + off);  off += (size_t)D_MODEL*D_FF*2;
    float* pv   = (float*)(ws + off); off += (size_t)4*D_MODEL*4;
    bf16*  xnb  = (bf16*)(ws + off);  off += (size_t)NROWS*D_MODEL*2;
    bf16*  xbf  = (bf16*)(ws + off);  off += (size_t)NROWS*D_MODEL*2;
    float* Sc   = (float*)(ws + off); off += (size_t)NBATCH*NCHUNK*D_MODEL*2*4;
    float* pref = (float*)(ws + off); off += (size_t)NBATCH*NCHUNK*D_MODEL*2*4;
    bf16*  x2b  = (bf16*)(ws + off);  off += (size_t)NROWS*D_MODEL*2;
    bf16*  x3b  = (bf16*)(ws + off);  off += (size_t)NROWS*D_MODEL*2;
    bf16*  hbuf = (bf16*)(ws + off);  off += (size_t)NROWS*D_FF*2;
    bf16*  ybuf = (bf16*)(ws + off);  off += (size_t)NROWS*D_MODEL*2;

    // weight casts to bf16 (x cast is fused into the first LayerNorm)
    cast4<<<1024, 256, 0, stream>>>((const float4*)fcw, (ushort4*)wfcb, D_MODEL*D_MODEL/4);
    cast4<<<4096, 256, 0, stream>>>((const float4*)w1,  (ushort4*)w1b,  D_FF*D_MODEL/4);
    cast4<<<4096, 256, 0, stream>>>((const float4*)w2,  (ushort4*)w2b,  D_MODEL*D_FF/4);

    compute_pvec<<<4, 256, 0, stream>>>(phz, pv);

    // xn = LN(x) -> bf16 (scan input); xbf = bf16(x) for the gate GEMM + residual
    ln_fused<<<NROWS, 256, 0, stream>>>(x, lng, lnb, xnb, xbf);

    // gate GEMM (pure): y = silu(x @ fc_w^T + fc_b) -> bf16  (only dep: xbf)
    gemm_bt<1><<<dim3(NROWS/BM, D_MODEL/BN), 256, 0, stream>>>(
        xbf, wfcb, fcb, nullptr, nullptr, ybuf, NROWS, D_MODEL, D_MODEL);

    // chunked linear scan: U[l] = p*U[l-1] + init_c*xn[l], U[-1]=hidden
    scan_pass1<<<dim3(4, NCHUNK, NBATCH), 256, 0, stream>>>(xnb, pv, pini, Sc);
    scan_prefix<<<dim3(4, NBATCH), 256, 0, stream>>>(Sc, pv, hr, hi, pref);
    // final pass fused with gate: writes cwp AND x2b = cwp_real*y + x
    scan_pass2g<<<dim3(4, NCHUNK, NBATCH), 256, 0, stream>>>(
        xnb, pv, pini, pref, ybuf, xbf, cwp, x2b, interleaved);

    // x3 = LN(x2b) -> bf16
    ln_b<<<NROWS, 256, 0, stream>>>(x2b, lng, lnb, x3b);

    // h = silu(x3 @ w1^T + b1) -> bf16   (256^2, 2-phase counted-vmcnt)
    gemm256p<<<dim3(NROWS/TM, D_FF/TN), 512, 0, stream>>>(
        x3b, w1b, b1, hbuf, NROWS, D_FF, D_MODEL);

    // out = h @ w2^T + b2 + x2   (128^2 depth-3 ring — best measured ffn2)
    gemm_bt<2><<<dim3(NROWS/BM, D_MODEL/BN), 256, 0, stream>>>(
        hbuf, w2b, b2, x2b, out, nullptr, NROWS, D_MODEL, D_FF);
}

// Round 23
// 261.734 us; speedup vs baseline: 1.0192x; 1.0192x over previous
//
#include <hip/hip_runtime.h>
#include <hip/hip_bf16.h>

#define D_MODEL 1024
#define D_FF    4096
#define SEQ_LEN 2048
#define NBATCH  4
#define NROWS   (NBATCH*SEQ_LEN)   // 8192
#define NCHUNK  32
#define CHUNK_L (SEQ_LEN/NCHUNK)   // 64
#define LN_EPS  1e-5f

typedef __hip_bfloat16 bf16;
typedef __attribute__((ext_vector_type(8))) short bf16x8;
typedef __attribute__((ext_vector_type(4))) float f32x4;

// async global->LDS, 16B per lane; LDS dest is wave-uniform base + lane*16
__device__ __forceinline__ void gload16(const bf16* g, bf16* l) {
    __builtin_amdgcn_global_load_lds(
        (const __attribute__((address_space(1))) void*)g,
        (__attribute__((address_space(3))) void*)l, 16, 0, 0);
}

// ---------------- merged weight cast f32 -> bf16 (3 segments, one launch) ----------------
#define CAST_N0 (D_MODEL*D_MODEL/4)            // fcw float4s
#define CAST_N1 (CAST_N0 + D_FF*D_MODEL/4)     // + w1
#define CAST_N2 (CAST_N1 + D_MODEL*D_FF/4)     // + w2
__global__ __launch_bounds__(256) void cast_all(const float4* __restrict__ fcw, ushort4* __restrict__ ofcw,
                                                const float4* __restrict__ w1,  ushort4* __restrict__ ow1,
                                                const float4* __restrict__ w2,  ushort4* __restrict__ ow2)
{
    int i = blockIdx.x * blockDim.x + threadIdx.x;
    if (i >= CAST_N2) return;
    const float4* src; ushort4* dst; int j;
    if (i < CAST_N0)      { src = fcw; dst = ofcw; j = i; }
    else if (i < CAST_N1) { src = w1;  dst = ow1;  j = i - CAST_N0; }
    else                  { src = w2;  dst = ow2;  j = i - CAST_N1; }
    float4 v = src[j];
    union { ushort4 u; bf16 b[4]; } cv;
    cv.b[0] = __float2bfloat16(v.x); cv.b[1] = __float2bfloat16(v.y);
    cv.b[2] = __float2bfloat16(v.z); cv.b[3] = __float2bfloat16(v.w);
    dst[j] = cv.u;
}

// ---------------- p, p^64 from phazor ----------------
__global__ void compute_pvec(const float* __restrict__ phz, float* __restrict__ pv) {
    int d = blockIdx.x * blockDim.x + threadIdx.x;
    if (d >= D_MODEL) return;
    float re = phz[2*d], im = phz[2*d+1];
    float r2 = re*re + im*im;
    float mag = expf(-r2);
    float pr, pim;
    if (r2 > 0.f) { float inv = mag / sqrtf(r2); pr = re*inv; pim = im*inv; }
    else          { pr = mag; pim = 0.f; }
    float ar = pr, ai = pim;
    #pragma unroll
    for (int i = 0; i < 6; i++) { float nr = ar*ar - ai*ai; float ni = 2.f*ar*ai; ar = nr; ai = ni; }
    pv[d]            = pr;
    pv[D_MODEL+d]    = pim;
    pv[2*D_MODEL+d]  = ar;
    pv[3*D_MODEL+d]  = ai;
}

// ---------------- LayerNorm: writes xn (bf16) + raw-x cast (bf16) ----------------
__global__ __launch_bounds__(256) void ln_fused(const float* __restrict__ x,
                                                const float* __restrict__ g,
                                                const float* __restrict__ bta,
                                                bf16*  __restrict__ outb,
                                                bf16*  __restrict__ rawb)
{
    int row = blockIdx.x;
    int tid = threadIdx.x;
    const float4* xr = (const float4*)(x + (size_t)row * D_MODEL);
    float4 v = xr[tid];
    if (rawb) {
        union { ushort4 u; bf16 b[4]; } cv;
        cv.b[0]=__float2bfloat16(v.x); cv.b[1]=__float2bfloat16(v.y);
        cv.b[2]=__float2bfloat16(v.z); cv.b[3]=__float2bfloat16(v.w);
        ((ushort4*)(rawb + (size_t)row * D_MODEL))[tid] = cv.u;
    }
    float s  = v.x + v.y + v.z + v.w;
    float s2 = v.x*v.x + v.y*v.y + v.z*v.z + v.w*v.w;
    for (int off = 32; off; off >>= 1) { s += __shfl_down(s, off); s2 += __shfl_down(s2, off); }
    __shared__ float red[8];
    int wid = tid >> 6, lane = tid & 63;
    if (lane == 0) { red[wid] = s; red[4+wid] = s2; }
    __syncthreads();
    if (tid == 0) {
        red[0] = red[0]+red[1]+red[2]+red[3];
        red[4] = red[4]+red[5]+red[6]+red[7];
    }
    __syncthreads();
    float mu  = red[0] * (1.f/D_MODEL);
    float var = red[4] * (1.f/D_MODEL) - mu*mu;
    float rstd = rsqrtf(var + LN_EPS);
    float4 gv = ((const float4*)g)[tid];
    float4 bv = ((const float4*)bta)[tid];
    union { ushort4 u; bf16 b[4]; } cv;
    cv.b[0] = __float2bfloat16((v.x-mu)*rstd*gv.x + bv.x);
    cv.b[1] = __float2bfloat16((v.y-mu)*rstd*gv.y + bv.y);
    cv.b[2] = __float2bfloat16((v.z-mu)*rstd*gv.z + bv.z);
    cv.b[3] = __float2bfloat16((v.w-mu)*rstd*gv.w + bv.w);
    ((ushort4*)(outb + (size_t)row * D_MODEL))[tid] = cv.u;
}

// ---------------- LN (bf16 in -> bf16 out): x3 = LN(x2b) ----------------
__global__ __launch_bounds__(256) void ln_b(const bf16* __restrict__ xin,
                                            const float* __restrict__ g,
                                            const float* __restrict__ bta,
                                            bf16*  __restrict__ outb)
{
    int row = blockIdx.x;
    int tid = threadIdx.x;
    size_t base = (size_t)row * D_MODEL + tid*4;
    union { ushort4 u; bf16 b[4]; } iv;
    iv.u = *(const ushort4*)(xin + base);
    float4 v;
    v.x = __bfloat162float(iv.b[0]); v.y = __bfloat162float(iv.b[1]);
    v.z = __bfloat162float(iv.b[2]); v.w = __bfloat162float(iv.b[3]);
    float s  = v.x + v.y + v.z + v.w;
    float s2 = v.x*v.x + v.y*v.y + v.z*v.z + v.w*v.w;
    for (int off = 32; off; off >>= 1) { s += __shfl_down(s, off); s2 += __shfl_down(s2, off); }
    __shared__ float red[8];
    int wid = tid >> 6, lane = tid & 63;
    if (lane == 0) { red[wid] = s; red[4+wid] = s2; }
    __syncthreads();
    if (tid == 0) {
        red[0] = red[0]+red[1]+red[2]+red[3];
        red[4] = red[4]+red[5]+red[6]+red[7];
    }
    __syncthreads();
    float mu  = red[0] * (1.f/D_MODEL);
    float var = red[4] * (1.f/D_MODEL) - mu*mu;
    float rstd = rsqrtf(var + LN_EPS);
    float4 gv = ((const float4*)g)[tid];
    float4 bv = ((const float4*)bta)[tid];
    union { ushort4 u; bf16 b[4]; } cv;
    cv.b[0] = __float2bfloat16((v.x-mu)*rstd*gv.x + bv.x);
    cv.b[1] = __float2bfloat16((v.y-mu)*rstd*gv.y + bv.y);
    cv.b[2] = __float2bfloat16((v.z-mu)*rstd*gv.z + bv.z);
    cv.b[3] = __float2bfloat16((v.w-mu)*rstd*gv.w + bv.w);
    *(ushort4*)(outb + base) = cv.u;
}

// ---------------- scan pass 1: per-chunk local state (zero init), bf16 input ----------------
__global__ __launch_bounds__(256) void scan_pass1(const bf16* __restrict__ xn,
                                                  const float* __restrict__ pv,
                                                  const float* __restrict__ pini,
                                                  float* __restrict__ Sc)
{
    int d = blockIdx.x * 256 + threadIdx.x;
    int c = blockIdx.y, b = blockIdx.z;
    float pr = pv[d], pim = pv[D_MODEL+d];
    float icr = pini[2*d], ici = pini[2*d+1];
    float Sr = 0.f, Si = 0.f;
    const bf16* xp = xn + ((size_t)b*SEQ_LEN + c*CHUNK_L) * D_MODEL + d;
    #pragma unroll 8
    for (int i = 0; i < CHUNK_L; i++) {
        float xv = __bfloat162float(xp[(size_t)i * D_MODEL]);
        float nr = pr*Sr - pim*Si + icr*xv;
        float ni = pr*Si + pim*Sr + ici*xv;
        Sr = nr; Si = ni;
    }
    size_t o = ((size_t)b*NCHUNK + c) * D_MODEL + d;
    Sc[2*o] = Sr; Sc[2*o+1] = Si;
}

// ---------------- scan pass 2: exclusive prefix over chunks (init = hidden) ----------------
__global__ __launch_bounds__(256) void scan_prefix(const float* __restrict__ Sc,
                                                   const float* __restrict__ pv,
                                                   const float* __restrict__ hr,
                                                   const float* __restrict__ hi,
                                                   float* __restrict__ pref)
{
    int d = blockIdx.x * 256 + threadIdx.x;
    int b = blockIdx.y;
    float qr = pv[2*D_MODEL+d], qi = pv[3*D_MODEL+d];   // p^64
    float Ur = hr[b*D_MODEL+d], Ui = hi[b*D_MODEL+d];
    for (int c = 0; c < NCHUNK; c++) {
        size_t o = ((size_t)b*NCHUNK + c) * D_MODEL + d;
        pref[2*o] = Ur; pref[2*o+1] = Ui;
        float sr = Sc[2*o], si = Sc[2*o+1];
        float nr = qr*Ur - qi*Ui + sr;
        float ni = qr*Ui + qi*Ur + si;
        Ur = nr; Ui = ni;
    }
}

// ---------------- scan pass 3 + gate fusion ----------------
// writes cwp = U (output 1) AND x2b = cwp_real * y + x (bf16)
__global__ __launch_bounds__(256) void scan_pass2g(const bf16* __restrict__ xn,
                                                   const float* __restrict__ pv,
                                                   const float* __restrict__ pini,
                                                   const float* __restrict__ pref,
                                                   const bf16* __restrict__ y,
                                                   const bf16* __restrict__ xb,
                                                   float* __restrict__ cwp,
                                                   bf16*  __restrict__ x2b,
                                                   int interleaved)
{
    int d = blockIdx.x * 256 + threadIdx.x;
    int c = blockIdx.y, b = blockIdx.z;
    float pr = pv[d], pim = pv[D_MODEL+d];
    float icr = pini[2*d], ici = pini[2*d+1];
    size_t po = ((size_t)b*NCHUNK + c) * D_MODEL + d;
    float Ur = pref[2*po], Ui = pref[2*po+1];
    size_t base = ((size_t)b*SEQ_LEN + c*CHUNK_L) * D_MODEL + d;
    const bf16* xp = xn + base;
    const bf16* yp = y  + base;
    const bf16* rp = xb + base;
    bf16* x2p = x2b + base;
    if (interleaved) {
        float2* cp = (float2*)cwp + base;
        #pragma unroll 8
        for (int i = 0; i < CHUNK_L; i++) {
            float xv = __bfloat162float(xp[(size_t)i * D_MODEL]);
            float nr = pr*Ur - pim*Ui + icr*xv;
            float ni = pr*Ui + pim*Ur + ici*xv;
            Ur = nr; Ui = ni;
            cp[(size_t)i * D_MODEL] = make_float2(Ur, Ui);
            float x2 = Ur * __bfloat162float(yp[(size_t)i * D_MODEL])
                     + __bfloat162float(rp[(size_t)i * D_MODEL]);
            x2p[(size_t)i * D_MODEL] = __float2bfloat16(x2);
        }
    } else {
        float* cp = cwp + base;
        #pragma unroll 8
        for (int i = 0; i < CHUNK_L; i++) {
            float xv = __bfloat162float(xp[(size_t)i * D_MODEL]);
            float nr = pr*Ur - pim*Ui + icr*xv;
            float ni = pr*Ui + pim*Ur + ici*xv;
            Ur = nr; Ui = ni;
            cp[(size_t)i * D_MODEL] = Ur;
            float x2 = Ur * __bfloat162float(yp[(size_t)i * D_MODEL])
                     + __bfloat162float(rp[(size_t)i * D_MODEL]);
            x2p[(size_t)i * D_MODEL] = __float2bfloat16(x2);
        }
    }
}

// ---------------- shared epilogue ----------------
template<int EPI>
__device__ __forceinline__ void epi_store(float v, size_t idx,
                                          const bf16* e0b, float* outf, bf16* outb)
{
    if (EPI == 1) {
        float yv = v / (1.f + __expf(-v));
        outb[idx] = __float2bfloat16(yv);
    } else {
        outf[idx] = v + __bfloat162float(e0b[idx]);
    }
}

// ---------------- bf16 MFMA GEMM 128x128: depth-3 LDS pipeline (r6/r8-proven) ----------------
#define BM 128
#define BN 128
#define BK 32

template<int EPI>
__global__ __launch_bounds__(256) void gemm_bt(const bf16* __restrict__ A,
                                               const bf16* __restrict__ Bt,
                                               const float* __restrict__ bias,
                                               const bf16* __restrict__ e0b,
                                               float* __restrict__ outf,
                                               bf16*  __restrict__ outb,
                                               int M, int N, int K)
{
    __shared__ __align__(16) bf16 As[3][BM*BK];
    __shared__ __align__(16) bf16 Bs[3][BM*BK];
    int tid = threadIdx.x;
    int m0 = blockIdx.x * BM;
    int n0 = blockIdx.y * BN;

    int wid = tid >> 6, lane = tid & 63;
    int wm = (wid >> 1) * 64, wn = (wid & 1) * 64;
    int lr = lane & 15;
    int lkc = lane >> 4;

    int rl = lane >> 2;
    int cS = (lane & 3) ^ ((rl >> 1) & 3);
    const bf16* gA0 = A  + (size_t)(m0 +      wid*16 + rl) * K + cS*8;
    const bf16* gA1 = A  + (size_t)(m0 + 64 + wid*16 + rl) * K + cS*8;
    const bf16* gB0 = Bt + (size_t)(n0 +      wid*16 + rl) * K + cS*8;
    const bf16* gB1 = Bt + (size_t)(n0 + 64 + wid*16 + rl) * K + cS*8;
    int lo0 = (     wid*16) * BK;
    int lo1 = (64 + wid*16) * BK;

    int keyr = (lr >> 1) & 3;
    int cR = (lkc ^ keyr) * 8;
    int offA[4], offB[4];
    #pragma unroll
    for (int i = 0; i < 4; i++) {
        offA[i] = (wm + i*16 + lr) * BK + cR;
        offB[i] = (wn + i*16 + lr) * BK + cR;
    }

    int nt = K / BK;
    auto stage = [&](int slot, int tile) {
        int k0 = tile * BK;
        gload16(gA0 + k0, &As[slot][lo0]);
        gload16(gA1 + k0, &As[slot][lo1]);
        gload16(gB0 + k0, &Bs[slot][lo0]);
        gload16(gB1 + k0, &Bs[slot][lo1]);
    };
    f32x4 acc[4][4] = {};
    auto compute = [&](int slot) {
        bf16x8 af[4], bfv[4];
        #pragma unroll
        for (int i = 0; i < 4; i++) {
            af[i]  = *(const bf16x8*)&As[slot][offA[i]];
            bfv[i] = *(const bf16x8*)&Bs[slot][offB[i]];
        }
        #pragma unroll
        for (int i = 0; i < 4; i++)
            #pragma unroll
            for (int j = 0; j < 4; j++)
                acc[i][j] = __builtin_amdgcn_mfma_f32_16x16x32_bf16(af[i], bfv[j], acc[i][j], 0, 0, 0);
    };

    stage(0, 0); stage(1, 1); stage(2, 2);

    int s = 0;
    for (int t = 0; t < nt - 3; ++t) {
        asm volatile("s_waitcnt vmcnt(8)" ::: "memory");
        __builtin_amdgcn_s_barrier();
        __builtin_amdgcn_sched_barrier(0);
        compute(s);
        asm volatile("" ::: "memory");
        __builtin_amdgcn_s_barrier();
        stage(s, t + 3);
        s = (s == 2) ? 0 : s + 1;
    }
    asm volatile("s_waitcnt vmcnt(8)" ::: "memory");
    __builtin_amdgcn_s_barrier();
    __builtin_amdgcn_sched_barrier(0);
    compute(s);
    s = (s == 2) ? 0 : s + 1;
    asm volatile("s_waitcnt vmcnt(4)" ::: "memory");
    __builtin_amdgcn_s_barrier();
    __builtin_amdgcn_sched_barrier(0);
    compute(s);
    s = (s == 2) ? 0 : s + 1;
    asm volatile("s_waitcnt vmcnt(0)" ::: "memory");
    __builtin_amdgcn_s_barrier();
    __builtin_amdgcn_sched_barrier(0);
    compute(s);

    int mrow = 4 * (lane >> 4);
    #pragma unroll
    for (int i = 0; i < 4; i++) {
        #pragma unroll
        for (int j = 0; j < 4; j++) {
            int nb = n0 + wn + j*16 + lr;
            float bb = bias[nb];
            #pragma unroll
            for (int r = 0; r < 4; r++) {
                int m = m0 + wm + i*16 + mrow + r;
                size_t idx = (size_t)m * N + nb;
                epi_store<EPI>(acc[i][j][r] + bb, idx, e0b, outf, outb);
            }
        }
    }
}

// ---------------- bf16 MFMA GEMM 256x256: 2-phase counted-vmcnt pipeline (r13-verified) ----------------
#define TM 256
#define TN 256

__global__ __launch_bounds__(512, 2) void gemm256p(const bf16* __restrict__ A,
                                                   const bf16* __restrict__ Bt,
                                                   const float* __restrict__ bias,
                                                   bf16* __restrict__ outb,
                                                   int M, int N, int K)
{
    __shared__ __align__(16) bf16 As[3][TM*BK];
    __shared__ __align__(16) bf16 Bs[3][TN*BK];
    int tid = threadIdx.x;
    int m0 = blockIdx.x * TM;
    int n0 = blockIdx.y * TN;

    int wid = tid >> 6, lane = tid & 63;
    int wr = wid >> 2, wc = wid & 3;       // 2 x 4 wave grid
    int wm = wr * 128, wn = wc * 64;
    int lr = lane & 15;
    int lkc = lane >> 4;

    int rs = tid >> 2;                     // 0..127
    int cS = (tid & 3) ^ ((rs >> 1) & 3);
    const bf16* gA = A  + (size_t)m0 * K + cS*8;
    const bf16* gB = Bt + (size_t)n0 * K + cS*8;
    int ldst = tid * 8;

    int keyr = (lr >> 1) & 3;
    int cR = (lkc ^ keyr) * 8;
    int offA[8], offB[4];
    #pragma unroll
    for (int i = 0; i < 8; i++) offA[i] = (wm + i*16 + lr) * BK + cR;
    #pragma unroll
    for (int j = 0; j < 4; j++) offB[j] = (wn + j*16 + lr) * BK + cR;

    int nt = K / BK;                       // 32 for K=1024
    auto stA = [&](int slot, int tile) {
        int k0 = tile * BK;
        gload16(gA + (size_t)rs * K + k0,         &As[slot][ldst]);
        gload16(gA + (size_t)(128 + rs) * K + k0, &As[slot][4096 + ldst]);
    };
    auto stB = [&](int slot, int tile) {
        int k0 = tile * BK;
        gload16(gB + (size_t)rs * K + k0,         &Bs[slot][ldst]);
        gload16(gB + (size_t)(128 + rs) * K + k0, &Bs[slot][4096 + ldst]);
    };

    f32x4 acc[8][4] = {};
    stA(0, 0); stB(0, 0); stA(1, 1); stB(1, 1); stB(2, 2);

    int s = 0;
    for (int t = 0; t < nt; ++t) {
        int sA = (s >= 1) ? s - 1 : 2;     // (s+2)%3
        if (t < nt - 2)       { asm volatile("s_waitcnt vmcnt(6)" ::: "memory"); }
        else if (t == nt - 2) { asm volatile("s_waitcnt vmcnt(4)" ::: "memory"); }
        else                  { asm volatile("s_waitcnt vmcnt(0)" ::: "memory"); }
        __builtin_amdgcn_s_barrier();
        asm volatile("" ::: "memory");
        bf16x8 af0[4], bfv[4];
        #pragma unroll
        for (int i = 0; i < 4; i++) af0[i] = *(const bf16x8*)&As[s][offA[i]];
        #pragma unroll
        for (int j = 0; j < 4; j++) bfv[j] = *(const bf16x8*)&Bs[s][offB[j]];
        if (t + 2 < nt) stA(sA, t + 2);
        asm volatile("s_waitcnt lgkmcnt(0)" ::: "memory");
        __builtin_amdgcn_sched_barrier(0);
        __builtin_amdgcn_s_setprio(1);
        #pragma unroll
        for (int i = 0; i < 4; i++)
            #pragma unroll
            for (int j = 0; j < 4; j++)
                acc[i][j] = __builtin_amdgcn_mfma_f32_16x16x32_bf16(af0[i], bfv[j], acc[i][j], 0, 0, 0);
        __builtin_amdgcn_s_setprio(0);
        __builtin_amdgcn_s_barrier();
        asm volatile("" ::: "memory");
        bf16x8 af1[4];
        #pragma unroll
        for (int i = 0; i < 4; i++) af1[i] = *(const bf16x8*)&As[s][offA[4+i]];
        if (t + 3 < nt) stB(s, t + 3);
        asm volatile("s_waitcnt lgkmcnt(0)" ::: "memory");
        __builtin_amdgcn_sched_barrier(0);
        __builtin_amdgcn_s_setprio(1);
        #pragma unroll
        for (int i = 0; i < 4; i++)
            #pragma unroll
            for (int j = 0; j < 4; j++)
                acc[4+i][j] = __builtin_amdgcn_mfma_f32_16x16x32_bf16(af1[i], bfv[j], acc[4+i][j], 0, 0, 0);
        __builtin_amdgcn_s_setprio(0);
        s = (s == 2) ? 0 : s + 1;
    }
    asm volatile("s_waitcnt vmcnt(0)" ::: "memory");

    int mrow = 4 * (lane >> 4);
    #pragma unroll
    for (int i = 0; i < 8; i++) {
        #pragma unroll
        for (int j = 0; j < 4; j++) {
            int nb = n0 + wn + j*16 + lr;
            float bb = bias[nb];
            #pragma unroll
            for (int r = 0; r < 4; r++) {
                int m = m0 + wm + i*16 + mrow + r;
                size_t idx = (size_t)m * N + nb;
                float v = acc[i][j][r] + bb;
                float yv = v / (1.f + __expf(-v));
                outb[idx] = __float2bfloat16(yv);
            }
        }
    }
}

extern "C" void kernel_launch(void* const* d_in, const int* in_sizes, int n_in,
                              void* d_out, int out_size, void* d_ws, size_t ws_size,
                              hipStream_t stream)
{
    const float* x    = (const float*)d_in[0];
    const float* hr   = (const float*)d_in[1];
    const float* hi   = (const float*)d_in[2];
    const float* pini = (const float*)d_in[3];
    const float* phz  = (const float*)d_in[4];
    const float* fcw  = (const float*)d_in[5];
    const float* fcb  = (const float*)d_in[6];
    const float* w1   = (const float*)d_in[7];
    const float* b1   = (const float*)d_in[8];
    const float* w2   = (const float*)d_in[9];
    const float* b2   = (const float*)d_in[10];
    const float* lng  = (const float*)d_in[11];
    const float* lnb  = (const float*)d_in[12];

    float* out = (float*)d_out;
    float* cwp = out + (size_t)NROWS * D_MODEL;
    int interleaved = (out_size >= NROWS * D_MODEL * 3) ? 1 : 0;

    char* ws = (char*)d_ws;
    size_t off = 0;
    bf16*  wfcb = (bf16*)(ws + off);  off += (size_t)D_MODEL*D_MODEL*2;
    bf16*  w1b  = (bf16*)(ws + off);  off += (size_t)D_FF*D_MODEL*2;
    bf16*  w2b  = (bf16*)(ws + off);  off += (size_t)D_MODEL*D_FF*2;
    float* pv   = (float*)(ws + off); off += (size_t)4*D_MODEL*4;
    bf16*  xnb  = (bf16*)(ws + off);  off += (size_t)NROWS*D_MODEL*2;
    bf16*  xbf  = (bf16*)(ws + off);  off += (size_t)NROWS*D_MODEL*2;
    float* Sc   = (float*)(ws + off); off += (size_t)NBATCH*NCHUNK*D_MODEL*2*4;
    float* pref = (float*)(ws + off); off += (size_t)NBATCH*NCHUNK*D_MODEL*2*4;
    bf16*  x2b  = (bf16*)(ws + off);  off += (size_t)NROWS*D_MODEL*2;
    bf16*  x3b  = (bf16*)(ws + off);  off += (size_t)NROWS*D_MODEL*2;
    bf16*  hbuf = (bf16*)(ws + off);  off += (size_t)NROWS*D_FF*2;
    bf16*  ybuf = (bf16*)(ws + off);  off += (size_t)NROWS*D_MODEL*2;

    // all weight casts in one launch
    cast_all<<<(CAST_N2 + 255) / 256, 256, 0, stream>>>(
        (const float4*)fcw, (ushort4*)wfcb,
        (const float4*)w1,  (ushort4*)w1b,
        (const float4*)w2,  (ushort4*)w2b);

    compute_pvec<<<4, 256, 0, stream>>>(phz, pv);

    // xn = LN(x) -> bf16 (scan input); xbf = bf16(x) for the gate GEMM + residual
    ln_fused<<<NROWS, 256, 0, stream>>>(x, lng, lnb, xnb, xbf);

    // gate GEMM (pure): y = silu(x @ fc_w^T + fc_b) -> bf16  (only dep: xbf)
    gemm_bt<1><<<dim3(NROWS/BM, D_MODEL/BN), 256, 0, stream>>>(
        xbf, wfcb, fcb, nullptr, nullptr, ybuf, NROWS, D_MODEL, D_MODEL);

    // chunked linear scan: U[l] = p*U[l-1] + init_c*xn[l], U[-1]=hidden
    scan_pass1<<<dim3(4, NCHUNK, NBATCH), 256, 0, stream>>>(xnb, pv, pini, Sc);
    scan_prefix<<<dim3(4, NBATCH), 256, 0, stream>>>(Sc, pv, hr, hi, pref);
    // final pass fused with gate: writes cwp AND x2b = cwp_real*y + x
    scan_pass2g<<<dim3(4, NCHUNK, NBATCH), 256, 0, stream>>>(
        xnb, pv, pini, pref, ybuf, xbf, cwp, x2b, interleaved);

    // x3 = LN(x2b) -> bf16
    ln_b<<<NROWS, 256, 0, stream>>>(x2b, lng, lnb, x3b);

    // h = silu(x3 @ w1^T + b1) -> bf16   (256^2, 2-phase counted-vmcnt)
    gemm256p<<<dim3(NROWS/TM, D_FF/TN), 512, 0, stream>>>(
        x3b, w1b, b1, hbuf, NROWS, D_FF, D_MODEL);

    // out = h @ w2^T + b2 + x2   (128^2 depth-3 ring — best measured ffn2)
    gemm_bt<2><<<dim3(NROWS/BM, D_MODEL/BN), 256, 0, stream>>>(
        hbuf, w2b, b2, x2b, out, nullptr, NROWS, D_MODEL, D_FF);
}

// Round 24
// 261.600 us; speedup vs baseline: 1.0197x; 1.0005x over previous
//
#include <hip/hip_runtime.h>
#include <hip/hip_bf16.h>

#define D_MODEL 1024
#define D_FF    4096
#define SEQ_LEN 2048
#define NBATCH  4
#define NROWS   (NBATCH*SEQ_LEN)   // 8192
#define NCHUNK  32
#define CHUNK_L (SEQ_LEN/NCHUNK)   // 64
#define LN_EPS  1e-5f

typedef __hip_bfloat16 bf16;
typedef __attribute__((ext_vector_type(8))) short bf16x8;
typedef __attribute__((ext_vector_type(4))) float f32x4;

// async global->LDS, 16B per lane; LDS dest is wave-uniform base + lane*16
__device__ __forceinline__ void gload16(const bf16* g, bf16* l) {
    __builtin_amdgcn_global_load_lds(
        (const __attribute__((address_space(1))) void*)g,
        (__attribute__((address_space(3))) void*)l, 16, 0, 0);
}

// ---------------- merged weight cast f32 -> bf16 (3 segments, one launch) ----------------
#define CAST_N0 (D_MODEL*D_MODEL/4)            // fcw float4s
#define CAST_N1 (CAST_N0 + D_FF*D_MODEL/4)     // + w1
#define CAST_N2 (CAST_N1 + D_MODEL*D_FF/4)     // + w2
__global__ __launch_bounds__(256) void cast_all(const float4* __restrict__ fcw, ushort4* __restrict__ ofcw,
                                                const float4* __restrict__ w1,  ushort4* __restrict__ ow1,
                                                const float4* __restrict__ w2,  ushort4* __restrict__ ow2)
{
    int i = blockIdx.x * blockDim.x + threadIdx.x;
    if (i >= CAST_N2) return;
    const float4* src; ushort4* dst; int j;
    if (i < CAST_N0)      { src = fcw; dst = ofcw; j = i; }
    else if (i < CAST_N1) { src = w1;  dst = ow1;  j = i - CAST_N0; }
    else                  { src = w2;  dst = ow2;  j = i - CAST_N1; }
    float4 v = src[j];
    union { ushort4 u; bf16 b[4]; } cv;
    cv.b[0] = __float2bfloat16(v.x); cv.b[1] = __float2bfloat16(v.y);
    cv.b[2] = __float2bfloat16(v.z); cv.b[3] = __float2bfloat16(v.w);
    dst[j] = cv.u;
}

// ---------------- p, p^64 from phazor ----------------
__global__ void compute_pvec(const float* __restrict__ phz, float* __restrict__ pv) {
    int d = blockIdx.x * blockDim.x + threadIdx.x;
    if (d >= D_MODEL) return;
    float re = phz[2*d], im = phz[2*d+1];
    float r2 = re*re + im*im;
    float mag = expf(-r2);
    float pr, pim;
    if (r2 > 0.f) { float inv = mag / sqrtf(r2); pr = re*inv; pim = im*inv; }
    else          { pr = mag; pim = 0.f; }
    float ar = pr, ai = pim;
    #pragma unroll
    for (int i = 0; i < 6; i++) { float nr = ar*ar - ai*ai; float ni = 2.f*ar*ai; ar = nr; ai = ni; }
    pv[d]            = pr;
    pv[D_MODEL+d]    = pim;
    pv[2*D_MODEL+d]  = ar;
    pv[3*D_MODEL+d]  = ai;
}

// ---------------- LayerNorm: writes xn (bf16) + raw-x cast (bf16) ----------------
__global__ __launch_bounds__(256) void ln_fused(const float* __restrict__ x,
                                                const float* __restrict__ g,
                                                const float* __restrict__ bta,
                                                bf16*  __restrict__ outb,
                                                bf16*  __restrict__ rawb)
{
    int row = blockIdx.x;
    int tid = threadIdx.x;
    const float4* xr = (const float4*)(x + (size_t)row * D_MODEL);
    float4 v = xr[tid];
    if (rawb) {
        union { ushort4 u; bf16 b[4]; } cv;
        cv.b[0]=__float2bfloat16(v.x); cv.b[1]=__float2bfloat16(v.y);
        cv.b[2]=__float2bfloat16(v.z); cv.b[3]=__float2bfloat16(v.w);
        ((ushort4*)(rawb + (size_t)row * D_MODEL))[tid] = cv.u;
    }
    float s  = v.x + v.y + v.z + v.w;
    float s2 = v.x*v.x + v.y*v.y + v.z*v.z + v.w*v.w;
    for (int off = 32; off; off >>= 1) { s += __shfl_down(s, off); s2 += __shfl_down(s2, off); }
    __shared__ float red[8];
    int wid = tid >> 6, lane = tid & 63;
    if (lane == 0) { red[wid] = s; red[4+wid] = s2; }
    __syncthreads();
    if (tid == 0) {
        red[0] = red[0]+red[1]+red[2]+red[3];
        red[4] = red[4]+red[5]+red[6]+red[7];
    }
    __syncthreads();
    float mu  = red[0] * (1.f/D_MODEL);
    float var = red[4] * (1.f/D_MODEL) - mu*mu;
    float rstd = rsqrtf(var + LN_EPS);
    float4 gv = ((const float4*)g)[tid];
    float4 bv = ((const float4*)bta)[tid];
    union { ushort4 u; bf16 b[4]; } cv;
    cv.b[0] = __float2bfloat16((v.x-mu)*rstd*gv.x + bv.x);
    cv.b[1] = __float2bfloat16((v.y-mu)*rstd*gv.y + bv.y);
    cv.b[2] = __float2bfloat16((v.z-mu)*rstd*gv.z + bv.z);
    cv.b[3] = __float2bfloat16((v.w-mu)*rstd*gv.w + bv.w);
    ((ushort4*)(outb + (size_t)row * D_MODEL))[tid] = cv.u;
}

// ---------------- LN (bf16 in -> bf16 out): x3 = LN(x2b) ----------------
__global__ __launch_bounds__(256) void ln_b(const bf16* __restrict__ xin,
                                            const float* __restrict__ g,
                                            const float* __restrict__ bta,
                                            bf16*  __restrict__ outb)
{
    int row = blockIdx.x;
    int tid = threadIdx.x;
    size_t base = (size_t)row * D_MODEL + tid*4;
    union { ushort4 u; bf16 b[4]; } iv;
    iv.u = *(const ushort4*)(xin + base);
    float4 v;
    v.x = __bfloat162float(iv.b[0]); v.y = __bfloat162float(iv.b[1]);
    v.z = __bfloat162float(iv.b[2]); v.w = __bfloat162float(iv.b[3]);
    float s  = v.x + v.y + v.z + v.w;
    float s2 = v.x*v.x + v.y*v.y + v.z*v.z + v.w*v.w;
    for (int off = 32; off; off >>= 1) { s += __shfl_down(s, off); s2 += __shfl_down(s2, off); }
    __shared__ float red[8];
    int wid = tid >> 6, lane = tid & 63;
    if (lane == 0) { red[wid] = s; red[4+wid] = s2; }
    __syncthreads();
    if (tid == 0) {
        red[0] = red[0]+red[1]+red[2]+red[3];
        red[4] = red[4]+red[5]+red[6]+red[7];
    }
    __syncthreads();
    float mu  = red[0] * (1.f/D_MODEL);
    float var = red[4] * (1.f/D_MODEL) - mu*mu;
    float rstd = rsqrtf(var + LN_EPS);
    float4 gv = ((const float4*)g)[tid];
    float4 bv = ((const float4*)bta)[tid];
    union { ushort4 u; bf16 b[4]; } cv;
    cv.b[0] = __float2bfloat16((v.x-mu)*rstd*gv.x + bv.x);
    cv.b[1] = __float2bfloat16((v.y-mu)*rstd*gv.y + bv.y);
    cv.b[2] = __float2bfloat16((v.z-mu)*rstd*gv.z + bv.z);
    cv.b[3] = __float2bfloat16((v.w-mu)*rstd*gv.w + bv.w);
    *(ushort4*)(outb + base) = cv.u;
}

// ---------------- scan pass 1: per-chunk local state (zero init), bf16 input ----------------
__global__ __launch_bounds__(256) void scan_pass1(const bf16* __restrict__ xn,
                                                  const float* __restrict__ pv,
                                                  const float* __restrict__ pini,
                                                  float* __restrict__ Sc)
{
    int d = blockIdx.x * 256 + threadIdx.x;
    int c = blockIdx.y, b = blockIdx.z;
    float pr = pv[d], pim = pv[D_MODEL+d];
    float icr = pini[2*d], ici = pini[2*d+1];
    float Sr = 0.f, Si = 0.f;
    const bf16* xp = xn + ((size_t)b*SEQ_LEN + c*CHUNK_L) * D_MODEL + d;
    #pragma unroll 8
    for (int i = 0; i < CHUNK_L; i++) {
        float xv = __bfloat162float(xp[(size_t)i * D_MODEL]);
        float nr = pr*Sr - pim*Si + icr*xv;
        float ni = pr*Si + pim*Sr + ici*xv;
        Sr = nr; Si = ni;
    }
    size_t o = ((size_t)b*NCHUNK + c) * D_MODEL + d;
    Sc[2*o] = Sr; Sc[2*o+1] = Si;
}

// ---------------- scan pass 2: exclusive prefix over chunks (init = hidden) ----------------
__global__ __launch_bounds__(256) void scan_prefix(const float* __restrict__ Sc,
                                                   const float* __restrict__ pv,
                                                   const float* __restrict__ hr,
                                                   const float* __restrict__ hi,
                                                   float* __restrict__ pref)
{
    int d = blockIdx.x * 256 + threadIdx.x;
    int b = blockIdx.y;
    float qr = pv[2*D_MODEL+d], qi = pv[3*D_MODEL+d];   // p^64
    float Ur = hr[b*D_MODEL+d], Ui = hi[b*D_MODEL+d];
    for (int c = 0; c < NCHUNK; c++) {
        size_t o = ((size_t)b*NCHUNK + c) * D_MODEL + d;
        pref[2*o] = Ur; pref[2*o+1] = Ui;
        float sr = Sc[2*o], si = Sc[2*o+1];
        float nr = qr*Ur - qi*Ui + sr;
        float ni = qr*Ui + qi*Ur + si;
        Ur = nr; Ui = ni;
    }
}

// ---------------- scan pass 3 + gate fusion ----------------
// writes cwp = U (output 1) AND x2b = cwp_real * y + x (bf16)
__global__ __launch_bounds__(256) void scan_pass2g(const bf16* __restrict__ xn,
                                                   const float* __restrict__ pv,
                                                   const float* __restrict__ pini,
                                                   const float* __restrict__ pref,
                                                   const bf16* __restrict__ y,
                                                   const bf16* __restrict__ xb,
                                                   float* __restrict__ cwp,
                                                   bf16*  __restrict__ x2b,
                                                   int interleaved)
{
    int d = blockIdx.x * 256 + threadIdx.x;
    int c = blockIdx.y, b = blockIdx.z;
    float pr = pv[d], pim = pv[D_MODEL+d];
    float icr = pini[2*d], ici = pini[2*d+1];
    size_t po = ((size_t)b*NCHUNK + c) * D_MODEL + d;
    float Ur = pref[2*po], Ui = pref[2*po+1];
    size_t base = ((size_t)b*SEQ_LEN + c*CHUNK_L) * D_MODEL + d;
    const bf16* xp = xn + base;
    const bf16* yp = y  + base;
    const bf16* rp = xb + base;
    bf16* x2p = x2b + base;
    if (interleaved) {
        float2* cp = (float2*)cwp + base;
        #pragma unroll 8
        for (int i = 0; i < CHUNK_L; i++) {
            float xv = __bfloat162float(xp[(size_t)i * D_MODEL]);
            float nr = pr*Ur - pim*Ui + icr*xv;
            float ni = pr*Ui + pim*Ur + ici*xv;
            Ur = nr; Ui = ni;
            cp[(size_t)i * D_MODEL] = make_float2(Ur, Ui);
            float x2 = Ur * __bfloat162float(yp[(size_t)i * D_MODEL])
                     + __bfloat162float(rp[(size_t)i * D_MODEL]);
            x2p[(size_t)i * D_MODEL] = __float2bfloat16(x2);
        }
    } else {
        float* cp = cwp + base;
        #pragma unroll 8
        for (int i = 0; i < CHUNK_L; i++) {
            float xv = __bfloat162float(xp[(size_t)i * D_MODEL]);
            float nr = pr*Ur - pim*Ui + icr*xv;
            float ni = pr*Ui + pim*Ur + ici*xv;
            Ur = nr; Ui = ni;
            cp[(size_t)i * D_MODEL] = Ur;
            float x2 = Ur * __bfloat162float(yp[(size_t)i * D_MODEL])
                     + __bfloat162float(rp[(size_t)i * D_MODEL]);
            x2p[(size_t)i * D_MODEL] = __float2bfloat16(x2);
        }
    }
}

// ---------------- shared epilogue ----------------
template<int EPI>
__device__ __forceinline__ void epi_store(float v, size_t idx,
                                          const bf16* e0b, float* outf, bf16* outb)
{
    if (EPI == 1) {
        float yv = v / (1.f + __expf(-v));
        outb[idx] = __float2bfloat16(yv);
    } else {
        outf[idx] = v + __bfloat162float(e0b[idx]);
    }
}

// ---------------- bf16 MFMA GEMM 128x128: depth-3 LDS pipeline (r6/r8-proven) ----------------
#define BM 128
#define BN 128
#define BK 32

template<int EPI>
__global__ __launch_bounds__(256) void gemm_bt(const bf16* __restrict__ A,
                                               const bf16* __restrict__ Bt,
                                               const float* __restrict__ bias,
                                               const bf16* __restrict__ e0b,
                                               float* __restrict__ outf,
                                               bf16*  __restrict__ outb,
                                               int M, int N, int K)
{
    __shared__ __align__(16) bf16 As[3][BM*BK];
    __shared__ __align__(16) bf16 Bs[3][BM*BK];
    int tid = threadIdx.x;
    int m0 = blockIdx.x * BM;
    int n0 = blockIdx.y * BN;

    int wid = tid >> 6, lane = tid & 63;
    int wm = (wid >> 1) * 64, wn = (wid & 1) * 64;
    int lr = lane & 15;
    int lkc = lane >> 4;

    int rl = lane >> 2;
    int cS = (lane & 3) ^ ((rl >> 1) & 3);
    const bf16* gA0 = A  + (size_t)(m0 +      wid*16 + rl) * K + cS*8;
    const bf16* gA1 = A  + (size_t)(m0 + 64 + wid*16 + rl) * K + cS*8;
    const bf16* gB0 = Bt + (size_t)(n0 +      wid*16 + rl) * K + cS*8;
    const bf16* gB1 = Bt + (size_t)(n0 + 64 + wid*16 + rl) * K + cS*8;
    int lo0 = (     wid*16) * BK;
    int lo1 = (64 + wid*16) * BK;

    int keyr = (lr >> 1) & 3;
    int cR = (lkc ^ keyr) * 8;
    int offA[4], offB[4];
    #pragma unroll
    for (int i = 0; i < 4; i++) {
        offA[i] = (wm + i*16 + lr) * BK + cR;
        offB[i] = (wn + i*16 + lr) * BK + cR;
    }

    int nt = K / BK;
    auto stage = [&](int slot, int tile) {
        int k0 = tile * BK;
        gload16(gA0 + k0, &As[slot][lo0]);
        gload16(gA1 + k0, &As[slot][lo1]);
        gload16(gB0 + k0, &Bs[slot][lo0]);
        gload16(gB1 + k0, &Bs[slot][lo1]);
    };
    f32x4 acc[4][4] = {};
    auto compute = [&](int slot) {
        bf16x8 af[4], bfv[4];
        #pragma unroll
        for (int i = 0; i < 4; i++) {
            af[i]  = *(const bf16x8*)&As[slot][offA[i]];
            bfv[i] = *(const bf16x8*)&Bs[slot][offB[i]];
        }
        #pragma unroll
        for (int i = 0; i < 4; i++)
            #pragma unroll
            for (int j = 0; j < 4; j++)
                acc[i][j] = __builtin_amdgcn_mfma_f32_16x16x32_bf16(af[i], bfv[j], acc[i][j], 0, 0, 0);
    };

    stage(0, 0); stage(1, 1); stage(2, 2);

    int s = 0;
    for (int t = 0; t < nt - 3; ++t) {
        asm volatile("s_waitcnt vmcnt(8)" ::: "memory");
        __builtin_amdgcn_s_barrier();
        __builtin_amdgcn_sched_barrier(0);
        compute(s);
        asm volatile("" ::: "memory");
        __builtin_amdgcn_s_barrier();
        stage(s, t + 3);
        s = (s == 2) ? 0 : s + 1;
    }
    asm volatile("s_waitcnt vmcnt(8)" ::: "memory");
    __builtin_amdgcn_s_barrier();
    __builtin_amdgcn_sched_barrier(0);
    compute(s);
    s = (s == 2) ? 0 : s + 1;
    asm volatile("s_waitcnt vmcnt(4)" ::: "memory");
    __builtin_amdgcn_s_barrier();
    __builtin_amdgcn_sched_barrier(0);
    compute(s);
    s = (s == 2) ? 0 : s + 1;
    asm volatile("s_waitcnt vmcnt(0)" ::: "memory");
    __builtin_amdgcn_s_barrier();
    __builtin_amdgcn_sched_barrier(0);
    compute(s);

    int mrow = 4 * (lane >> 4);
    #pragma unroll
    for (int i = 0; i < 4; i++) {
        #pragma unroll
        for (int j = 0; j < 4; j++) {
            int nb = n0 + wn + j*16 + lr;
            float bb = bias[nb];
            #pragma unroll
            for (int r = 0; r < 4; r++) {
                int m = m0 + wm + i*16 + mrow + r;
                size_t idx = (size_t)m * N + nb;
                epi_store<EPI>(acc[i][j][r] + bb, idx, e0b, outf, outb);
            }
        }
    }
}

// ---------------- bf16 MFMA GEMM 256x256: 2-phase counted-vmcnt pipeline (r13-verified) ----------------
#define TM 256
#define TN 256

__global__ __launch_bounds__(512, 2) void gemm256p(const bf16* __restrict__ A,
                                                   const bf16* __restrict__ Bt,
                                                   const float* __restrict__ bias,
                                                   bf16* __restrict__ outb,
                                                   int M, int N, int K)
{
    __shared__ __align__(16) bf16 As[3][TM*BK];
    __shared__ __align__(16) bf16 Bs[3][TN*BK];
    int tid = threadIdx.x;
    int m0 = blockIdx.x * TM;
    int n0 = blockIdx.y * TN;

    int wid = tid >> 6, lane = tid & 63;
    int wr = wid >> 2, wc = wid & 3;       // 2 x 4 wave grid
    int wm = wr * 128, wn = wc * 64;
    int lr = lane & 15;
    int lkc = lane >> 4;

    int rs = tid >> 2;                     // 0..127
    int cS = (tid & 3) ^ ((rs >> 1) & 3);
    const bf16* gA = A  + (size_t)m0 * K + cS*8;
    const bf16* gB = Bt + (size_t)n0 * K + cS*8;
    int ldst = tid * 8;

    int keyr = (lr >> 1) & 3;
    int cR = (lkc ^ keyr) * 8;
    int offA[8], offB[4];
    #pragma unroll
    for (int i = 0; i < 8; i++) offA[i] = (wm + i*16 + lr) * BK + cR;
    #pragma unroll
    for (int j = 0; j < 4; j++) offB[j] = (wn + j*16 + lr) * BK + cR;

    int nt = K / BK;                       // 32 for K=1024
    auto stA = [&](int slot, int tile) {
        int k0 = tile * BK;
        gload16(gA + (size_t)rs * K + k0,         &As[slot][ldst]);
        gload16(gA + (size_t)(128 + rs) * K + k0, &As[slot][4096 + ldst]);
    };
    auto stB = [&](int slot, int tile) {
        int k0 = tile * BK;
        gload16(gB + (size_t)rs * K + k0,         &Bs[slot][ldst]);
        gload16(gB + (size_t)(128 + rs) * K + k0, &Bs[slot][4096 + ldst]);
    };

    f32x4 acc[8][4] = {};
    stA(0, 0); stB(0, 0); stA(1, 1); stB(1, 1); stB(2, 2);

    int s = 0;
    for (int t = 0; t < nt; ++t) {
        int sA = (s >= 1) ? s - 1 : 2;     // (s+2)%3
        if (t < nt - 2)       { asm volatile("s_waitcnt vmcnt(6)" ::: "memory"); }
        else if (t == nt - 2) { asm volatile("s_waitcnt vmcnt(4)" ::: "memory"); }
        else                  { asm volatile("s_waitcnt vmcnt(0)" ::: "memory"); }
        __builtin_amdgcn_s_barrier();
        asm volatile("" ::: "memory");
        bf16x8 af0[4], bfv[4];
        #pragma unroll
        for (int i = 0; i < 4; i++) af0[i] = *(const bf16x8*)&As[s][offA[i]];
        #pragma unroll
        for (int j = 0; j < 4; j++) bfv[j] = *(const bf16x8*)&Bs[s][offB[j]];
        if (t + 2 < nt) stA(sA, t + 2);
        asm volatile("s_waitcnt lgkmcnt(0)" ::: "memory");
        __builtin_amdgcn_sched_barrier(0);
        __builtin_amdgcn_s_setprio(1);
        #pragma unroll
        for (int i = 0; i < 4; i++)
            #pragma unroll
            for (int j = 0; j < 4; j++)
                acc[i][j] = __builtin_amdgcn_mfma_f32_16x16x32_bf16(af0[i], bfv[j], acc[i][j], 0, 0, 0);
        __builtin_amdgcn_s_setprio(0);
        __builtin_amdgcn_s_barrier();
        asm volatile("" ::: "memory");
        bf16x8 af1[4];
        #pragma unroll
        for (int i = 0; i < 4; i++) af1[i] = *(const bf16x8*)&As[s][offA[4+i]];
        if (t + 3 < nt) stB(s, t + 3);
        asm volatile("s_waitcnt lgkmcnt(0)" ::: "memory");
        __builtin_amdgcn_sched_barrier(0);
        __builtin_amdgcn_s_setprio(1);
        #pragma unroll
        for (int i = 0; i < 4; i++)
            #pragma unroll
            for (int j = 0; j < 4; j++)
                acc[4+i][j] = __builtin_amdgcn_mfma_f32_16x16x32_bf16(af1[i], bfv[j], acc[4+i][j], 0, 0, 0);
        __builtin_amdgcn_s_setprio(0);
        s = (s == 2) ? 0 : s + 1;
    }
    asm volatile("s_waitcnt vmcnt(0)" ::: "memory");

    int mrow = 4 * (lane >> 4);
    #pragma unroll
    for (int i = 0; i < 8; i++) {
        #pragma unroll
        for (int j = 0; j < 4; j++) {
            int nb = n0 + wn + j*16 + lr;
            float bb = bias[nb];
            #pragma unroll
            for (int r = 0; r < 4; r++) {
                int m = m0 + wm + i*16 + mrow + r;
                size_t idx = (size_t)m * N + nb;
                float v = acc[i][j][r] + bb;
                float yv = v / (1.f + __expf(-v));
                outb[idx] = __float2bfloat16(yv);
            }
        }
    }
}

extern "C" void kernel_launch(void* const* d_in, const int* in_sizes, int n_in,
                              void* d_out, int out_size, void* d_ws, size_t ws_size,
                              hipStream_t stream)
{
    const float* x    = (const float*)d_in[0];
    const float* hr   = (const float*)d_in[1];
    const float* hi   = (const float*)d_in[2];
    const float* pini = (const float*)d_in[3];
    const float* phz  = (const float*)d_in[4];
    const float* fcw  = (const float*)d_in[5];
    const float* fcb  = (const float*)d_in[6];
    const float* w1   = (const float*)d_in[7];
    const float* b1   = (const float*)d_in[8];
    const float* w2   = (const float*)d_in[9];
    const float* b2   = (const float*)d_in[10];
    const float* lng  = (const float*)d_in[11];
    const float* lnb  = (const float*)d_in[12];

    float* out = (float*)d_out;
    float* cwp = out + (size_t)NROWS * D_MODEL;
    int interleaved = (out_size >= NROWS * D_MODEL * 3) ? 1 : 0;

    char* ws = (char*)d_ws;
    size_t off = 0;
    bf16*  wfcb = (bf16*)(ws + off);  off += (size_t)D_MODEL*D_MODEL*2;
    bf16*  w1b  = (bf16*)(ws + off);  off += (size_t)D_FF*D_MODEL*2;
    bf16*  w2b  = (bf16*)(ws + off);  off += (size_t)D_MODEL*D_FF*2;
    float* pv   = (float*)(ws + off); off += (size_t)4*D_MODEL*4;
    bf16*  xnb  = (bf16*)(ws + off);  off += (size_t)NROWS*D_MODEL*2;
    bf16*  xbf  = (bf16*)(ws + off);  off += (size_t)NROWS*D_MODEL*2;
    float* Sc   = (float*)(ws + off); off += (size_t)NBATCH*NCHUNK*D_MODEL*2*4;
    float* pref = (float*)(ws + off); off += (size_t)NBATCH*NCHUNK*D_MODEL*2*4;
    bf16*  x2b  = (bf16*)(ws + off);  off += (size_t)NROWS*D_MODEL*2;
    bf16*  x3b  = (bf16*)(ws + off);  off += (size_t)NROWS*D_MODEL*2;
    bf16*  hbuf = (bf16*)(ws + off);  off += (size_t)NROWS*D_FF*2;
    bf16*  ybuf = (bf16*)(ws + off);  off += (size_t)NROWS*D_MODEL*2;

    // all weight casts in one launch
    cast_all<<<(CAST_N2 + 255) / 256, 256, 0, stream>>>(
        (const float4*)fcw, (ushort4*)wfcb,
        (const float4*)w1,  (ushort4*)w1b,
        (const float4*)w2,  (ushort4*)w2b);

    compute_pvec<<<4, 256, 0, stream>>>(phz, pv);

    // xn = LN(x) -> bf16 (scan input); xbf = bf16(x) for the gate GEMM + residual
    ln_fused<<<NROWS, 256, 0, stream>>>(x, lng, lnb, xnb, xbf);

    // gate GEMM (pure): y = silu(x @ fc_w^T + fc_b) -> bf16  (only dep: xbf)
    gemm_bt<1><<<dim3(NROWS/BM, D_MODEL/BN), 256, 0, stream>>>(
        xbf, wfcb, fcb, nullptr, nullptr, ybuf, NROWS, D_MODEL, D_MODEL);

    // chunked linear scan: U[l] = p*U[l-1] + init_c*xn[l], U[-1]=hidden
    scan_pass1<<<dim3(4, NCHUNK, NBATCH), 256, 0, stream>>>(xnb, pv, pini, Sc);
    scan_prefix<<<dim3(4, NBATCH), 256, 0, stream>>>(Sc, pv, hr, hi, pref);
    // final pass fused with gate: writes cwp AND x2b = cwp_real*y + x
    scan_pass2g<<<dim3(4, NCHUNK, NBATCH), 256, 0, stream>>>(
        xnb, pv, pini, pref, ybuf, xbf, cwp, x2b, interleaved);

    // x3 = LN(x2b) -> bf16
    ln_b<<<NROWS, 256, 0, stream>>>(x2b, lng, lnb, x3b);

    // h = silu(x3 @ w1^T + b1) -> bf16   (256^2, 2-phase counted-vmcnt)
    gemm256p<<<dim3(NROWS/TM, D_FF/TN), 512, 0, stream>>>(
        x3b, w1b, b1, hbuf, NROWS, D_FF, D_MODEL);

    // out = h @ w2^T + b2 + x2   (128^2 depth-3 ring — best measured ffn2)
    gemm_bt<2><<<dim3(NROWS/BM, D_MODEL/BN), 256, 0, stream>>>(
        hbuf, w2b, b2, x2b, out, nullptr, NROWS, D_MODEL, D_FF);
}